// Round 8
// baseline (344.483 us; speedup 1.0000x reference)
//
#include <hip/hip_runtime.h>

typedef unsigned short u16;
typedef unsigned int   u32;

typedef __attribute__((ext_vector_type(8))) short short8;   // 8 bf16 (4 VGPRs)
typedef __attribute__((ext_vector_type(4))) float f32x4;    // MFMA acc

union Frag { u32 u[4]; short8 s; };

__device__ __forceinline__ u32 fbits(float f){ union{float f;u32 u;}x; x.f=f; return x.u; }
__device__ __forceinline__ float bitsf(u32 u){ union{u32 u;float f;}x; x.u=u; return x.f; }
// pack two f32 -> packed bf16 pair by TRUNCATION (1 v_perm)
__device__ __forceinline__ u32 pack_trunc(float a, float b){
    return __builtin_amdgcn_perm(fbits(b), fbits(a), 0x07060302u);
}
__device__ __forceinline__ u32 bf16_rne(float a){
    u32 u = fbits(a); return (u + 0x7FFFu + ((u >> 16) & 1u)) >> 16;
}
__device__ __forceinline__ u32 pack_rne(float a, float b){
    return bf16_rne(a) | (bf16_rne(b) << 16);
}
__device__ __forceinline__ float sigmoidf_(float x){
    return __builtin_amdgcn_rcpf(1.0f + __expf(-x));
}
__device__ __forceinline__ float tanhf_(float x){
    return 1.0f - 2.0f * __builtin_amdgcn_rcpf(__expf(2.0f * x) + 1.0f);
}

// Per-block LDS (2 waves): ~43.3 KB -> 2 blocks/CU (86.5 KB of 160 KB).
struct __align__(16) SharedMem {
    union {
        u32 alo[192 * 36];   // 27648 B — Whh lo-half, packed bf16 pairs (loop only)
        struct {             // 9476 B — tail weights, staged after recurrence
            float wl[1152];
            float bl[16];
            float wcf[640];
            float bcf[20];
            float wcc[80];
            float bcc[20];
            float wcm[400];
            float bcm[20];
            float wfin[20];
            float bfin;
        } tw;
    };
    float wih[192 * 4];     // 3072 B
    float gbias[128];       // bih+bhh, rows 0..127 (r,z) -> acc init
    float gnh[64];          // bhh rows 128..191 -> accN init
    float gnb[64];          // bih rows 128..191 -> gi_n base
    float h[2][16 * 68];    // 8704 B, per-wave hidden state [s][k]
    float u[2][64];         // per-wave u[s*4+c]
    float line[2][128];
    float pp[2][128];
};

__global__ __launch_bounds__(128, 2)
void FRAPRQ_fused_kernel(
    const float* __restrict__ feat,       // (B,16)
    const float* __restrict__ hist,       // (B,64,24)
    const int*   __restrict__ relation,   // (8,7)
    const float* __restrict__ emb_phase,  // (2,4)
    const float* __restrict__ Wv,         // (4,1)
    const float* __restrict__ bv,         // (4)
    const float* __restrict__ Wh,         // (4,3)
    const float* __restrict__ bh,         // (4)
    const float* __restrict__ Wih,        // (192,4)
    const float* __restrict__ Whh,        // (192,64)
    const float* __restrict__ bih,        // (192)
    const float* __restrict__ bhh,        // (192)
    const float* __restrict__ Wl,         // (16,72)
    const float* __restrict__ bl,         // (16)
    const float* __restrict__ emb_const,  // (2,4)
    const float* __restrict__ Wcf,        // (20,32)
    const float* __restrict__ bcf,        // (20)
    const float* __restrict__ Wcc,        // (20,4)
    const float* __restrict__ bcc,        // (20)
    const float* __restrict__ Wcm,        // (20,20)
    const float* __restrict__ bcm,        // (20)
    const float* __restrict__ Wfin,      // (1,20)
    const float* __restrict__ bfin,      // (1)
    float* __restrict__ out)             // (B,8)
{
    __shared__ SharedMem sm;
    const int tid  = threadIdx.x;        // 0..127
    const int wave = tid >> 6;           // 0..1
    const int lane = tid & 63;
    const int sq   = lane & 15;          // MFMA column: local seq
    const int q    = lane >> 4;          // MFMA quad
    const int b_base = (blockIdx.x * 2 + wave) * 2;

    // ---- stage: Whh lo-half (packed bf16 pairs, row stride 36 u32) ----
    for (int i = tid; i < 192 * 32; i += 128){
        const int row = i >> 5, P = i & 31;
        const float w0 = Whh[row * 64 + 2 * P];
        const float w1 = Whh[row * 64 + 2 * P + 1];
        const u32 h0 = bf16_rne(w0), h1 = bf16_rne(w1);
        const float l0 = w0 - bitsf(h0 << 16);
        const float l1 = w1 - bitsf(h1 << 16);
        sm.alo[row * 36 + P] = pack_rne(l0, l1);
    }
    for (int i = tid; i < 768; i += 128) sm.wih[i] = Wih[i];
    if (tid < 128) sm.gbias[tid] = bih[tid] + bhh[tid];
    if (tid < 64){
        sm.gnh[tid] = bhh[128 + tid];
        sm.gnb[tid] = bih[128 + tid];
    }

    float* hw = &sm.h[wave][0];
    float* uw = &sm.u[wave][0];
    for (int i = lane; i < 16 * 68; i += 64) hw[i] = 0.0f;

    // ---- A hi-fragments in VGPRs (96): row 16mt+sq, k = 32kt+8q+j ----
    Frag ahi[12][2];
    #pragma unroll
    for (int mt = 0; mt < 12; ++mt){
        const int row = 16 * mt + sq;
        #pragma unroll
        for (int kt = 0; kt < 2; ++kt){
            const float* wp = Whh + row * 64 + 32 * kt + 8 * q;
            float f[8];
            #pragma unroll
            for (int i = 0; i < 8; ++i) f[i] = wp[i];
            #pragma unroll
            for (int p = 0; p < 4; ++p)
                ahi[mt][kt].u[p] = pack_rne(f[2*p], f[2*p+1]);
        }
    }

    // ---- u path: lane computes u[s=sq][c=q] ----
    const int bs = b_base + (sq >> 3);
    const int ls = sq & 7;
    const float* hb = hist + (size_t)bs * 1536;
    const float wh0 = Wh[q*3+0], wh1 = Wh[q*3+1], wh2 = Wh[q*3+2], bhc = bh[q];
    float x0 = hb[ls], x1 = hb[ls + 8], x2 = hb[ls + 16];

    float hreg[4][4];
    #pragma unroll
    for (int m = 0; m < 4; ++m)
        #pragma unroll
        for (int r = 0; r < 4; ++r) hreg[m][r] = 0.0f;

    __syncthreads();   // staging visible

    #pragma unroll 1
    for (int t = 0; t < 64; ++t){
        const int tn = (t + 1 < 64) ? (t + 1) : 63;
        const float p0 = hb[tn*24 + ls], p1 = hb[tn*24 + ls + 8], p2 = hb[tn*24 + ls + 16];

        // u(t): wave-synchronous LDS exchange
        uw[sq * 4 + q] = sigmoidf_(fmaf(wh0, x0, fmaf(wh1, x1, fmaf(wh2, x2, bhc))));
        const float4 u4 = *(const float4*)&uw[sq * 4];

        // accumulators init = biases (LDS broadcast reads, no VALU)
        f32x4 acc[8], accN[4];
        #pragma unroll
        for (int mt = 0; mt < 8; ++mt) acc[mt] = *(const f32x4*)&sm.gbias[16*mt + 4*q];
        #pragma unroll
        for (int m = 0; m < 4; ++m)   accN[m] = *(const f32x4*)&sm.gnh[16*m + 4*q];

        // MFMA: D += Whh·h with split (AhiBhi + AhiBlo + AloBhi)
        #pragma unroll
        for (int kt = 0; kt < 2; ++kt){
            const float4 hA = *(const float4*)&hw[sq*68 + 32*kt + 8*q];
            const float4 hB = *(const float4*)&hw[sq*68 + 32*kt + 8*q + 4];
            const float f[8] = {hA.x, hA.y, hA.z, hA.w, hB.x, hB.y, hB.z, hB.w};
            Frag bhi, blo;
            #pragma unroll
            for (int p = 0; p < 4; ++p){
                const u32 hi = pack_trunc(f[2*p], f[2*p+1]);
                bhi.u[p] = hi;
                const float l0 = f[2*p]   - bitsf((hi & 0xFFFFu) << 16);
                const float l1 = f[2*p+1] - bitsf(hi & 0xFFFF0000u);
                blo.u[p] = pack_trunc(l0, l1);
            }
            #pragma unroll
            for (int mt = 0; mt < 12; ++mt){
                Frag af;
                *(uint4*)af.u = *(const uint4*)&sm.alo[(16*mt + sq)*36 + 16*kt + 4*q];
                f32x4 tgt = (mt < 8) ? acc[mt] : accN[mt - 8];
                tgt = __builtin_amdgcn_mfma_f32_16x16x32_bf16(ahi[mt][kt].s, bhi.s, tgt, 0, 0, 0);
                tgt = __builtin_amdgcn_mfma_f32_16x16x32_bf16(ahi[mt][kt].s, blo.s, tgt, 0, 0, 0);
                tgt = __builtin_amdgcn_mfma_f32_16x16x32_bf16(af.s,          bhi.s, tgt, 0, 0, 0);
                if (mt < 8) acc[mt] = tgt; else accN[mt - 8] = tgt;
            }
        }

        // gates: gi dots (wih broadcast reads) fused into gate update, per m
        #pragma unroll
        for (int m = 0; m < 4; ++m){
            const float4 gnbv = *(const float4*)&sm.gnb[16*m + 4*q];
            float4 hnew;
            #pragma unroll
            for (int r = 0; r < 4; ++r){
                const float4 wr = *(const float4*)&sm.wih[(16*m       + 4*q + r) * 4];
                const float4 wz = *(const float4*)&sm.wih[(16*(m + 4) + 4*q + r) * 4];
                const float4 wn = *(const float4*)&sm.wih[(16*(m + 8) + 4*q + r) * 4];
                const float gir = fmaf(wr.x,u4.x, fmaf(wr.y,u4.y, fmaf(wr.z,u4.z, wr.w*u4.w)));
                const float giz = fmaf(wz.x,u4.x, fmaf(wz.y,u4.y, fmaf(wz.z,u4.z, wz.w*u4.w)));
                const float gin = fmaf(wn.x,u4.x, fmaf(wn.y,u4.y, fmaf(wn.z,u4.z,
                                  fmaf(wn.w,u4.w, ((const float*)&gnbv)[r]))));
                const float rr = sigmoidf_(acc[m][r]     + gir);
                const float zz = sigmoidf_(acc[m + 4][r] + giz);
                const float cand = tanhf_(fmaf(rr, accN[m][r], gin));
                const float hn = fmaf(zz, hreg[m][r] - cand, cand);
                hreg[m][r] = hn;
                ((float*)&hnew)[r] = hn;
            }
            *(float4*)&hw[sq*68 + 16*m + 4*q] = hnew;
        }

        x0 = p0; x1 = p1; x2 = p2;
    }
    __syncthreads();   // alo region dead; flip union to tail weights

    // ---- stage tail weights ----
    for (int i = tid; i < 1152; i += 128) sm.tw.wl[i]  = Wl[i];
    for (int i = tid; i <  640; i += 128) sm.tw.wcf[i] = Wcf[i];
    for (int i = tid; i <  400; i += 128) sm.tw.wcm[i] = Wcm[i];
    if (tid < 80) sm.tw.wcc[tid] = Wcc[tid];
    if (tid < 20){
        sm.tw.bcf[tid]  = bcf[tid];
        sm.tw.bcc[tid]  = bcc[tid];
        sm.tw.bcm[tid]  = bcm[tid];
        sm.tw.wfin[tid] = Wfin[tid];
    }
    if (tid < 16) sm.tw.bl[tid] = bl[tid];
    if (tid == 0) sm.tw.bfin = bfin[0];
    __syncthreads();

    // ---- tail: per-wave, 2 b's sequentially; wave-private LDS ----
    #pragma unroll 1
    for (int bb = 0; bb < 2; ++bb){
        const int b = b_base + bb;
        // Phase A
        {
            const int l = lane >> 3, o = lane & 7;
            float fv[8];
            const float vraw = feat[b * 16 + 8 + l];
            const int   bit  = ((int)feat[b * 16 + l]) & 1;
            #pragma unroll
            for (int c = 0; c < 4; ++c){
                fv[c]     = sigmoidf_(fmaf(vraw, Wv[c], bv[c]));
                fv[4 + c] = sigmoidf_(emb_phase[bit * 4 + c]);
            }
            const float* hrow = &hw[(bb * 8 + l) * 68];
            #pragma unroll
            for (int half = 0; half < 2; ++half){
                const int oo = o + half * 8;
                float acc = sm.tw.bl[oo];
                #pragma unroll
                for (int f = 0; f < 8; ++f) acc = fmaf(fv[f], sm.tw.wl[oo * 72 + f], acc);
                for (int k = 0; k < 64; ++k) acc = fmaf(hrow[k], sm.tw.wl[oo * 72 + 8 + k], acc);
                sm.line[wave][l * 16 + oo] = fmaxf(acc, 0.0f);
            }
        }
        __builtin_amdgcn_wave_barrier();
        // Phase B
        {
            const int p = lane >> 3, o = lane & 7;
            const int l0 = (0x64204501u >> (p * 4)) & 15;
            const int l1 = (0x75316723u >> (p * 4)) & 15;
            sm.pp[wave][p * 16 + o]     = sm.line[wave][l0 * 16 + o]     + sm.line[wave][l1 * 16 + o];
            sm.pp[wave][p * 16 + o + 8] = sm.line[wave][l0 * 16 + o + 8] + sm.line[wave][l1 * 16 + o + 8];
        }
        __builtin_amdgcn_wave_barrier();
        // Phase C
        if (lane < 56){
            const int p  = lane / 7;
            const int qi = lane - p * 7;
            const int jl = qi + (qi >= p ? 1 : 0);
            float fmv[32];
            #pragma unroll
            for (int f = 0; f < 16; ++f){
                fmv[f]      = sm.pp[wave][p  * 16 + f];
                fmv[16 + f] = sm.pp[wave][jl * 16 + f];
            }
            const int rel = relation[p * 7 + qi] & 1;
            float ce[4];
            #pragma unroll
            for (int c = 0; c < 4; ++c) ce[c] = emb_const[rel * 4 + c];
            float m[20];
            for (int o = 0; o < 20; ++o){
                float xf = sm.tw.bcf[o];
                #pragma unroll
                for (int f = 0; f < 32; ++f) xf = fmaf(fmv[f], sm.tw.wcf[o * 32 + f], xf);
                float yc = sm.tw.bcc[o];
                #pragma unroll
                for (int c = 0; c < 4; ++c) yc = fmaf(ce[c], sm.tw.wcc[o * 4 + c], yc);
                m[o] = fmaxf(xf, 0.0f) * fmaxf(yc, 0.0f);
            }
            float fin = sm.tw.bfin;
            for (int o = 0; o < 20; ++o){
                float zz = sm.tw.bcm[o];
                #pragma unroll
                for (int c = 0; c < 20; ++c) zz = fmaf(m[c], sm.tw.wcm[o * 20 + c], zz);
                fin = fmaf(fmaxf(zz, 0.0f), sm.tw.wfin[o], fin);
            }
            sm.line[wave][lane] = fin;   // line dead after Phase B
        }
        __builtin_amdgcn_wave_barrier();
        if (lane < 8){
            float acc = 0.0f;
            #pragma unroll
            for (int qq = 0; qq < 7; ++qq) acc += sm.line[wave][lane * 7 + qq];
            out[b * 8 + lane] = acc;
        }
        __builtin_amdgcn_wave_barrier();   // line reused next bb
    }
}

extern "C" void kernel_launch(void* const* d_in, const int* in_sizes, int n_in,
                              void* d_out, int out_size, void* d_ws, size_t ws_size,
                              hipStream_t stream) {
    (void)n_in; (void)d_ws; (void)ws_size; (void)out_size;
    const float* feat      = (const float*)d_in[0];
    const float* hist      = (const float*)d_in[1];
    const int*   relation  = (const int*)d_in[2];
    const float* emb_phase = (const float*)d_in[3];
    const float* Wv        = (const float*)d_in[4];
    const float* bv        = (const float*)d_in[5];
    const float* Wh        = (const float*)d_in[6];
    const float* bh        = (const float*)d_in[7];
    const float* Wih       = (const float*)d_in[8];
    const float* Whh       = (const float*)d_in[9];
    const float* bih       = (const float*)d_in[10];
    const float* bhh       = (const float*)d_in[11];
    const float* Wl        = (const float*)d_in[12];
    const float* bl        = (const float*)d_in[13];
    const float* emb_const = (const float*)d_in[14];
    const float* Wcf       = (const float*)d_in[15];
    const float* bcf       = (const float*)d_in[16];
    const float* Wcc       = (const float*)d_in[17];
    const float* bcc       = (const float*)d_in[18];
    const float* Wcm       = (const float*)d_in[19];
    const float* bcm       = (const float*)d_in[20];
    const float* Wfin      = (const float*)d_in[21];
    const float* bfin      = (const float*)d_in[22];
    float* out = (float*)d_out;

    const int B = in_sizes[0] / 16;     // 2048
    const int nblocks = B / 4;          // 512: 2 waves/block x 2 b/wave
    FRAPRQ_fused_kernel<<<nblocks, 128, 0, stream>>>(
        feat, hist, relation, emb_phase, Wv, bv, Wh, bh, Wih, Whh, bih, bhh,
        Wl, bl, emb_const, Wcf, bcf, Wcc, bcc, Wcm, bcm, Wfin, bfin, out);
}